// Round 7
// baseline (709.046 us; speedup 1.0000x reference)
//
#include <hip/hip_runtime.h>
#include <hip/hip_bf16.h>

#define NB 262144   // batch
#define KD 512      // in_dim
#define ED 10000    // embed_dim

typedef __attribute__((ext_vector_type(8))) short s8v;
typedef __attribute__((ext_vector_type(4))) float f4v;

typedef __attribute__((address_space(1))) const unsigned int gu32_t;
typedef __attribute__((address_space(3))) unsigned int lu32_t;

__device__ __forceinline__ short f2bf(float f) {
  union { __hip_bfloat16 h; short s; } u;
  u.h = __float2bfloat16(f);
  return u.s;
}

// ---------------- DIAGNOSTIC: strided 128B-granule read BW probe ----------------
// Replays R5's A-staging DRAM pattern: per wave-instruction, 8 rows x 128B at
// 2KB row stride (16B/lane, XOR-swizzled within the 128B slice). 5 passes over
// all of x (2.56 GB fetch >> 256MB L3). Register accumulate; sink into d_ws.
__global__ __launch_bounds__(512, 4) void diag_strided(const float* __restrict__ x,
                                                       float* __restrict__ sink) {
  const int tid = threadIdx.x;
  const int row_in = tid >> 3;       // 0..63 (row within 64-row block tile)
  const int q = tid & 7;             // 16B chunk within the 128B row-slice
  float4 acc = {0.f, 0.f, 0.f, 0.f};
  for (int pass = 0; pass < 5; ++pass) {
    int b = (int)((blockIdx.x + (unsigned)pass * 1637u) & 4095u);   // bijective shift
    const float* p = x + (((size_t)(b << 6) + row_in) << 9) + ((q ^ (row_in & 7)) << 2);
#pragma unroll
    for (int kt = 0; kt < 16; ++kt) {
      float4 v = *(const float4*)(p + (kt << 5));   // 16B at row-slice kt (128B/row granule)
      acc.x += v.x; acc.y += v.y; acc.z += v.z; acc.w += v.w;
    }
  }
  sink[blockIdx.x * 512 + tid] = acc.x + acc.y + acc.z + acc.w;
}

// ---------------- prep (merged): W pack + embT transpose ----------------
__global__ void prep_all(const float* __restrict__ Wlv, const float* __restrict__ Wmu,
                         unsigned short* __restrict__ wbf,
                         const float* __restrict__ We, const float* __restrict__ be,
                         float* __restrict__ embT) {
  __shared__ float t[32][129];
  if (blockIdx.x < 512) {
    int i = blockIdx.x * 256 + threadIdx.x;          // [0, 131072)
    int row = i >> 9, col = i & 511;
    float v = (row < 128) ? Wlv[(row << 9) | col] : Wmu[((row - 128) << 9) | col];
    union { __hip_bfloat16 h; unsigned short s; } u;
    u.h = __float2bfloat16(v);
    wbf[i] = u.s;
  } else {
    const int v0 = (blockIdx.x - 512) << 5;
#pragma unroll
    for (int j = 0; j < 16; ++j) {
      int idx = j * 256 + threadIdx.x;               // [0, 4096)
      int l = idx >> 5, vi = idx & 31;
      int v = v0 + vi;
      t[vi][l] = (v < ED) ? We[(size_t)l * ED + v] : 0.f;
    }
    __syncthreads();
#pragma unroll
    for (int j = 0; j < 16; ++j) {
      int idx = j * 256 + threadIdx.x;
      int v = idx >> 7, l = idx & 127;
      if (v0 + v < ED)
        embT[(size_t)(v0 + v) * 128 + l] = t[v][l] + be[l];
    }
  }
}

// ---------------- main GEMM: R5 structure verbatim (best known, 296.9us) ----------------
__global__ __launch_bounds__(512, 4) void gemm_heads(
    const float* __restrict__ x, const unsigned short* __restrict__ wbf,
    const float* __restrict__ blv, const float* __restrict__ bmu,
    const int* __restrict__ y, const float* __restrict__ embT,
    float* __restrict__ out, int doEmbed) {
  __shared__ char lds[3 * 24576];                    // 72 KB
  const int tid  = threadIdx.x;
  const int lane = tid & 63;
  const int wid  = tid >> 6;
  const int wm   = wid >> 2;   // 0..1
  const int wn   = wid & 3;    // 0..3
  const int gm   = blockIdx.x << 6;
  const int lr   = lane & 15;
  const int kg   = lane >> 4;

  const int arow = tid >> 3, aq = tid & 7;
  const unsigned aSrcBase = (unsigned)(arow << 9) + (unsigned)((aq ^ (arow & 7)) << 2);
  const unsigned aDst = (unsigned)(tid << 4);
  unsigned bSrcBase[2], bDst[2];
#pragma unroll
  for (int s = 0; s < 2; ++s) {
    int c = tid + (s << 9);
    int col = c >> 2, q = c & 3;
    int qp = q ^ ((col >> 1) & 3);
    bSrcBase[s] = (unsigned)(col << 9) + (unsigned)(qp << 3);
    bDst[s] = 8192u + (unsigned)(c << 4);
  }
  const float* xblk = x + ((size_t)gm << 9);

  unsigned offA[2][2], offB[4];
#pragma unroll
  for (int m = 0; m < 2; ++m) {
    int row = (wm << 5) + (m << 4) + lr;
    int sw = row & 7;
    offA[m][0] = (unsigned)(row << 7) + (unsigned)((((kg << 1))     ^ sw) << 4);
    offA[m][1] = (unsigned)(row << 7) + (unsigned)((((kg << 1) + 1) ^ sw) << 4);
  }
#pragma unroll
  for (int nt = 0; nt < 4; ++nt) {
    int col = (wn << 6) + (nt << 4) + lr;
    offB[nt] = 8192u + (unsigned)(col << 6) + (unsigned)((kg ^ ((col >> 1) & 3)) << 4);
  }

  f4v acc[2][4];
#pragma unroll
  for (int m = 0; m < 2; ++m)
#pragma unroll
    for (int nt = 0; nt < 4; ++nt) acc[m][nt] = (f4v)0.f;

#define ISSUE_STAGE(st)                                                            \
  {                                                                                \
    const int ke = (st) << 5;                                                      \
    char* sb = lds + ((st) % 3) * 24576;                                           \
    __builtin_amdgcn_global_load_lds((const gu32_t*)(xblk + aSrcBase + ke),        \
                                     (lu32_t*)(sb + aDst), 16, 0, 0);              \
    __builtin_amdgcn_global_load_lds((const gu32_t*)(wbf + bSrcBase[0] + ke),      \
                                     (lu32_t*)(sb + bDst[0]), 16, 0, 0);           \
    __builtin_amdgcn_global_load_lds((const gu32_t*)(wbf + bSrcBase[1] + ke),      \
                                     (lu32_t*)(sb + bDst[1]), 16, 0, 0);           \
  }

  ISSUE_STAGE(0)
  ISSUE_STAGE(1)
  asm volatile("s_waitcnt vmcnt(3)" ::: "memory");
  __builtin_amdgcn_s_barrier();

#pragma unroll
  for (int t = 0; t < 16; ++t) {
    if (t <= 13) ISSUE_STAGE(t + 2)
    const char* stage = lds + (t % 3) * 24576;
    s8v bfr[4];
#pragma unroll
    for (int nt = 0; nt < 4; ++nt)
      bfr[nt] = *(const s8v*)(stage + offB[nt]);
    s8v af[2];
#pragma unroll
    for (int m = 0; m < 2; ++m) {
      float4 a0 = *(const float4*)(stage + offA[m][0]);
      float4 a1 = *(const float4*)(stage + offA[m][1]);
      af[m][0] = f2bf(a0.x); af[m][1] = f2bf(a0.y); af[m][2] = f2bf(a0.z); af[m][3] = f2bf(a0.w);
      af[m][4] = f2bf(a1.x); af[m][5] = f2bf(a1.y); af[m][6] = f2bf(a1.z); af[m][7] = f2bf(a1.w);
    }
#pragma unroll
    for (int m = 0; m < 2; ++m)
#pragma unroll
      for (int nt = 0; nt < 4; ++nt)
        acc[m][nt] = __builtin_amdgcn_mfma_f32_16x16x32_bf16(af[m], bfr[nt], acc[m][nt], 0, 0, 0);
    asm volatile("s_waitcnt lgkmcnt(0)" ::: "memory");
    __builtin_amdgcn_sched_barrier(0);
    if (t <= 13)      { asm volatile("s_waitcnt vmcnt(3)" ::: "memory"); }
    else if (t == 14) { asm volatile("s_waitcnt vmcnt(0)" ::: "memory"); }
    if (t <= 14) __builtin_amdgcn_s_barrier();
  }
#undef ISSUE_STAGE

  const int rsub = kg << 2;
#pragma unroll
  for (int nt = 0; nt < 4; ++nt) {
    int col = (wn << 6) + (nt << 4) + lr;
    float bias = (col < 128) ? blv[col] : bmu[col - 128];
    float* ob = (col < 128) ? (out + col)
                            : (out + ((size_t)NB << 7) + (col - 128));
#pragma unroll
    for (int m = 0; m < 2; ++m) {
      int row0 = gm + (wm << 5) + (m << 4) + rsub;
#pragma unroll
      for (int r = 0; r < 4; ++r)
        ob[(size_t)(row0 + r) << 7] = acc[m][nt][r] + bias;
    }
  }

  if (doEmbed) {
    float* out3 = out + ((size_t)NB << 8);
    int r  = tid >> 3;            // 0..63
    int c0 = (tid & 7) << 4;      // 0..112 (floats)
    int row = gm + r;
    int v = y[row];
    const float4* src = (const float4*)(embT + (size_t)v * 128 + c0);
    float4* dst = (float4*)(out3 + ((size_t)row << 7) + c0);
#pragma unroll
    for (int j = 0; j < 4; ++j) dst[j] = src[j];
  }
}

// ---------------- fallbacks (only if ws_size too small) ----------------
__global__ void gemm_naive(const float* __restrict__ x,
                           const float* __restrict__ Wlv, const float* __restrict__ blv,
                           const float* __restrict__ Wmu, const float* __restrict__ bmu,
                           float* __restrict__ out) {
  __shared__ float xr[512];
  int b = blockIdx.x;
  for (int i = threadIdx.x; i < 512; i += 256) xr[i] = x[(size_t)b * 512 + i];
  __syncthreads();
  int c = threadIdx.x;
  const float* w = (c < 128) ? (Wlv + c * 512) : (Wmu + (c - 128) * 512);
  float s = 0.f;
  for (int k = 0; k < 512; ++k) s += xr[k] * w[k];
  s += (c < 128) ? blv[c] : bmu[c - 128];
  float* o = (c < 128) ? (out + (size_t)b * 128 + c)
                       : (out + ((size_t)NB << 7) + (size_t)b * 128 + (c - 128));
  *o = s;
}

__global__ void embed_direct(const int* __restrict__ y, const float* __restrict__ We,
                             const float* __restrict__ be, float* __restrict__ out3) {
  size_t t = (size_t)blockIdx.x * 256 + threadIdx.x;
  int b = (int)(t >> 7), l = (int)(t & 127);
  out3[t] = We[(size_t)l * ED + y[b]] + be[l];
}

extern "C" void kernel_launch(void* const* d_in, const int* in_sizes, int n_in,
                              void* d_out, int out_size, void* d_ws, size_t ws_size,
                              hipStream_t stream) {
  const float* x   = (const float*)d_in[0];
  const int*   y   = (const int*)d_in[1];
  const float* Wlv = (const float*)d_in[2];
  const float* blv = (const float*)d_in[3];
  const float* Wmu = (const float*)d_in[4];
  const float* bmu = (const float*)d_in[5];
  const float* We  = (const float*)d_in[6];
  const float* be  = (const float*)d_in[7];
  float* out  = (float*)d_out;
  float* out3 = out + ((size_t)NB << 8);

  const size_t needW = 256 * 512 * sizeof(unsigned short);          // 256 KB
  const size_t needE = needW + (size_t)ED * 128 * sizeof(float);    // + 5.12 MB
  const size_t diagOff = 16u * 1024 * 1024;                         // sink at +16MB
  const size_t needD = diagOff + (size_t)4096 * 512 * sizeof(float);
  unsigned short* wbf = (unsigned short*)d_ws;
  float* embT = (float*)((char*)d_ws + needW);

  // diagnostic probe (only if workspace permits; does not touch d_out)
  if (ws_size >= needD)
    diag_strided<<<4096, 512, 0, stream>>>(x, (float*)((char*)d_ws + diagOff));

  if (ws_size >= needE) {
    prep_all<<<512 + 313, 256, 0, stream>>>(Wlv, Wmu, wbf, We, be, embT);
    gemm_heads<<<NB / 64, 512, 0, stream>>>(x, wbf, blv, bmu, y, embT, out, 1);
  } else if (ws_size >= needW) {
    prep_all<<<512, 256, 0, stream>>>(Wlv, Wmu, wbf, We, be, (float*)d_ws);
    gemm_heads<<<NB / 64, 512, 0, stream>>>(x, wbf, blv, bmu, y, nullptr, out, 0);
    embed_direct<<<NB * 128 / 256, 256, 0, stream>>>(y, We, be, out3);
  } else {
    gemm_naive<<<NB, 256, 0, stream>>>(x, Wlv, blv, Wmu, bmu, out);
    embed_direct<<<NB * 128 / 256, 256, 0, stream>>>(y, We, be, out3);
  }
}

// Round 8
// 412.486 us; speedup vs baseline: 1.7190x; 1.7190x over previous
//
#include <hip/hip_runtime.h>
#include <hip/hip_bf16.h>

#define NB 262144   // batch
#define KD 512      // in_dim
#define ED 10000    // embed_dim

typedef __attribute__((ext_vector_type(8))) short s8v;
typedef __attribute__((ext_vector_type(4))) float f4v;

__device__ __forceinline__ short f2bf(float f) {
  union { __hip_bfloat16 h; short s; } u;
  u.h = __float2bfloat16(f);
  return u.s;
}

// ---------------- prep (merged): W pack + embT transpose ----------------
__global__ void prep_all(const float* __restrict__ Wlv, const float* __restrict__ Wmu,
                         unsigned short* __restrict__ wbf,
                         const float* __restrict__ We, const float* __restrict__ be,
                         float* __restrict__ embT) {
  __shared__ float t[32][129];
  if (blockIdx.x < 512) {
    int i = blockIdx.x * 256 + threadIdx.x;          // [0, 131072)
    int row = i >> 9, col = i & 511;
    float v = (row < 128) ? Wlv[(row << 9) | col] : Wmu[((row - 128) << 9) | col];
    union { __hip_bfloat16 h; unsigned short s; } u;
    u.h = __float2bfloat16(v);
    wbf[i] = u.s;
  } else {
    const int v0 = (blockIdx.x - 512) << 5;
#pragma unroll
    for (int j = 0; j < 16; ++j) {
      int idx = j * 256 + threadIdx.x;               // [0, 4096)
      int l = idx >> 5, vi = idx & 31;
      int v = v0 + vi;
      t[vi][l] = (v < ED) ? We[(size_t)l * ED + v] : 0.f;
    }
    __syncthreads();
#pragma unroll
    for (int j = 0; j < 16; ++j) {
      int idx = j * 256 + threadIdx.x;
      int v = idx >> 7, l = idx & 127;
      if (v0 + v < ED)
        embT[(size_t)(v0 + v) * 128 + l] = t[v][l] + be[l];
    }
  }
}

// ---------------- main GEMM ----------------
// BM=64, full-K one-shot A stage (bf16 in LDS, 64KB, swizzled, conflict-free),
// B bf16 direct from L2-resident wbf to registers. One barrier per block.
// 8 waves: wm 0..1 (32-row half), wn 0..3 (64-col group); wave tile 32x64.
__global__ __launch_bounds__(512, 4) void gemm_heads(
    const float* __restrict__ x, const unsigned short* __restrict__ wbf,
    const float* __restrict__ blv, const float* __restrict__ bmu,
    const int* __restrict__ y, const float* __restrict__ embT,
    float* __restrict__ out, int doEmbed) {
  __shared__ char lds[65536];                        // A bf16 [64 rows][1024B]
  const int tid  = threadIdx.x;
  const int lane = tid & 63;
  const int wid  = tid >> 6;
  const int wm   = wid >> 2;   // 0..1
  const int wn   = wid & 3;    // 0..3
  const int gm   = blockIdx.x << 6;
  const int lr   = lane & 15;
  const int kg   = lane >> 4;

  // ---- one-shot A stage: wave-contiguous 1KB global loads -> cvt -> swizzled LDS ----
  // wave wid covers x rows [gm+wid*8, gm+wid*8+8) = contiguous 16KB of x.
  // step j: 1KB at row (wid*8 + (j>>1)), half (j&1); lane holds 4 floats
  // (k = (j&1)*256 + lane*4). bf16 16B-chunk index c = (j&1)*32 + (lane>>1).
  // LDS byte = row*1024 + ((c ^ (row&7))<<4) + (lane&1)*8.   (read uses same XOR)
  {
    const char* xw = (const char*)x + (((size_t)gm) << 11) + ((unsigned)wid << 14);
#pragma unroll
    for (int j = 0; j < 16; ++j) {
      float4 v = *(const float4*)(xw + (j << 10) + (lane << 4));
      int row = (wid << 3) + (j >> 1);
      int c   = ((j & 1) << 5) + (lane >> 1);
      unsigned dst = (unsigned)(row << 10) + (unsigned)((c ^ (row & 7)) << 4)
                   + (unsigned)((lane & 1) << 3);
      short4 p;
      p.x = f2bf(v.x); p.y = f2bf(v.y); p.z = f2bf(v.z); p.w = f2bf(v.w);
      *(short4*)(lds + dst) = p;
    }
  }
  __syncthreads();

  // ---- B pointers: wave's 64 cols (4 groups of 16), 16B/lane/kt from L2-hot wbf
  const unsigned short* pb[4];
#pragma unroll
  for (int nt = 0; nt < 4; ++nt)
    pb[nt] = wbf + (((size_t)((wn << 6) + (nt << 4) + lr)) << 9) + (kg << 3);

  f4v acc[2][4];
#pragma unroll
  for (int m = 0; m < 2; ++m)
#pragma unroll
    for (int nt = 0; nt < 4; ++nt) acc[m][nt] = (f4v)0.f;

  // ---- barrier-free compute: 16 k-tiles of 32 ----
#pragma unroll
  for (int kt = 0; kt < 16; ++kt) {
    s8v bfr[4];
#pragma unroll
    for (int nt = 0; nt < 4; ++nt)
      bfr[nt] = *(const s8v*)(pb[nt] + (kt << 5));
    s8v af[2];
#pragma unroll
    for (int m = 0; m < 2; ++m) {
      int row = (wm << 5) + (m << 4) + lr;
      int c   = (kt << 2) + kg;
      af[m] = *(const s8v*)(lds + (row << 10) + ((c ^ (row & 7)) << 4));
    }
#pragma unroll
    for (int m = 0; m < 2; ++m)
#pragma unroll
      for (int nt = 0; nt < 4; ++nt)
        acc[m][nt] = __builtin_amdgcn_mfma_f32_16x16x32_bf16(af[m], bfr[nt], acc[m][nt], 0, 0, 0);
  }

  // ---- epilogue: C/D layout col=lane&15, row=(lane>>4)*4+r (validated r1/r4/r5)
  const int rsub = kg << 2;
#pragma unroll
  for (int nt = 0; nt < 4; ++nt) {
    int col = (wn << 6) + (nt << 4) + lr;
    float bias = (col < 128) ? blv[col] : bmu[col - 128];
    float* ob = (col < 128) ? (out + col)
                            : (out + ((size_t)NB << 7) + (col - 128));
#pragma unroll
    for (int m = 0; m < 2; ++m) {
      int row0 = gm + (wm << 5) + (m << 4) + rsub;
#pragma unroll
      for (int r = 0; r < 4; ++r)
        ob[(size_t)(row0 + r) << 7] = acc[m][nt][r] + bias;
    }
  }

  // ---- fused embed: this block's 64 rows; embT is L2-resident
  if (doEmbed) {
    float* out3 = out + ((size_t)NB << 8);
    int r  = tid >> 3;            // 0..63
    int c0 = (tid & 7) << 4;      // 0..112 (floats)
    int row = gm + r;
    int v = y[row];
    const float4* src = (const float4*)(embT + (size_t)v * 128 + c0);
    float4* dst = (float4*)(out3 + ((size_t)row << 7) + c0);
#pragma unroll
    for (int j = 0; j < 4; ++j) dst[j] = src[j];
  }
}

// ---------------- fallbacks (only if ws_size too small) ----------------
__global__ void gemm_naive(const float* __restrict__ x,
                           const float* __restrict__ Wlv, const float* __restrict__ blv,
                           const float* __restrict__ Wmu, const float* __restrict__ bmu,
                           float* __restrict__ out) {
  __shared__ float xr[512];
  int b = blockIdx.x;
  for (int i = threadIdx.x; i < 512; i += 256) xr[i] = x[(size_t)b * 512 + i];
  __syncthreads();
  int c = threadIdx.x;
  const float* w = (c < 128) ? (Wlv + c * 512) : (Wmu + (c - 128) * 512);
  float s = 0.f;
  for (int k = 0; k < 512; ++k) s += xr[k] * w[k];
  s += (c < 128) ? blv[c] : bmu[c - 128];
  float* o = (c < 128) ? (out + (size_t)b * 128 + c)
                       : (out + ((size_t)NB << 7) + (size_t)b * 128 + (c - 128));
  *o = s;
}

__global__ void embed_direct(const int* __restrict__ y, const float* __restrict__ We,
                             const float* __restrict__ be, float* __restrict__ out3) {
  size_t t = (size_t)blockIdx.x * 256 + threadIdx.x;
  int b = (int)(t >> 7), l = (int)(t & 127);
  out3[t] = We[(size_t)l * ED + y[b]] + be[l];
}

extern "C" void kernel_launch(void* const* d_in, const int* in_sizes, int n_in,
                              void* d_out, int out_size, void* d_ws, size_t ws_size,
                              hipStream_t stream) {
  const float* x   = (const float*)d_in[0];
  const int*   y   = (const int*)d_in[1];
  const float* Wlv = (const float*)d_in[2];
  const float* blv = (const float*)d_in[3];
  const float* Wmu = (const float*)d_in[4];
  const float* bmu = (const float*)d_in[5];
  const float* We  = (const float*)d_in[6];
  const float* be  = (const float*)d_in[7];
  float* out  = (float*)d_out;
  float* out3 = out + ((size_t)NB << 8);

  const size_t needW = 256 * 512 * sizeof(unsigned short);          // 256 KB
  const size_t needE = needW + (size_t)ED * 128 * sizeof(float);    // + 5.12 MB
  unsigned short* wbf = (unsigned short*)d_ws;
  float* embT = (float*)((char*)d_ws + needW);

  if (ws_size >= needE) {
    prep_all<<<512 + 313, 256, 0, stream>>>(Wlv, Wmu, wbf, We, be, embT);
    gemm_heads<<<NB / 64, 512, 0, stream>>>(x, wbf, blv, bmu, y, embT, out, 1);
  } else if (ws_size >= needW) {
    prep_all<<<512, 256, 0, stream>>>(Wlv, Wmu, wbf, We, be, (float*)d_ws);
    gemm_heads<<<NB / 64, 512, 0, stream>>>(x, wbf, blv, bmu, y, nullptr, out, 0);
    embed_direct<<<NB * 128 / 256, 256, 0, stream>>>(y, We, be, out3);
  } else {
    gemm_naive<<<NB, 256, 0, stream>>>(x, Wlv, blv, Wmu, bmu, out);
    embed_direct<<<NB * 128 / 256, 256, 0, stream>>>(y, We, be, out3);
  }
}

// Round 9
// 298.480 us; speedup vs baseline: 2.3755x; 1.3820x over previous
//
#include <hip/hip_runtime.h>
#include <hip/hip_bf16.h>

#define NB 262144   // batch
#define KD 512      // in_dim
#define ED 10000    // embed_dim

typedef __attribute__((ext_vector_type(8))) short s8v;
typedef __attribute__((ext_vector_type(4))) float f4v;

typedef __attribute__((address_space(1))) const unsigned int gu32_t;
typedef __attribute__((address_space(3))) unsigned int lu32_t;

__device__ __forceinline__ short f2bf(float f) {
  union { __hip_bfloat16 h; short s; } u;
  u.h = __float2bfloat16(f);
  return u.s;
}

// ---------------- prep (merged): W pack + embT transpose ----------------
__global__ void prep_all(const float* __restrict__ Wlv, const float* __restrict__ Wmu,
                         unsigned short* __restrict__ wbf,
                         const float* __restrict__ We, const float* __restrict__ be,
                         float* __restrict__ embT) {
  __shared__ float t[32][129];
  if (blockIdx.x < 512) {
    int i = blockIdx.x * 256 + threadIdx.x;          // [0, 131072)
    int row = i >> 9, col = i & 511;
    float v = (row < 128) ? Wlv[(row << 9) | col] : Wmu[((row - 128) << 9) | col];
    union { __hip_bfloat16 h; unsigned short s; } u;
    u.h = __float2bfloat16(v);
    wbf[i] = u.s;
  } else {
    const int v0 = (blockIdx.x - 512) << 5;
#pragma unroll
    for (int j = 0; j < 16; ++j) {
      int idx = j * 256 + threadIdx.x;               // [0, 4096)
      int l = idx >> 5, vi = idx & 31;
      int v = v0 + vi;
      t[vi][l] = (v < ED) ? We[(size_t)l * ED + v] : 0.f;
    }
    __syncthreads();
#pragma unroll
    for (int j = 0; j < 16; ++j) {
      int idx = j * 256 + threadIdx.x;
      int v = idx >> 7, l = idx & 127;
      if (v0 + v < ED)
        embT[(size_t)(v0 + v) * 128 + l] = t[v][l] + be[l];
    }
  }
}

// ---------------- main GEMM: R5 sync skeleton, 16KB stage, 3 blocks/CU ----------------
// Grid 8192: row-block rb (64 rows) x col-half h (128 cols). BK=32, 16 tiles.
// Stage (16KB) = A fp32 [64][32] (8KB, swz) + B bf16 [128][32] (8KB, swz).
// 3 stages = 48KB -> 3 blocks/CU = 24 waves (75% occ).
// 8 waves: wm 0..1 (32 rows) x wn 0..3 (32 cols); wave tile 32x32; acc 16 VGPR.
__global__ __launch_bounds__(512, 6) void gemm_heads(
    const float* __restrict__ x, const unsigned short* __restrict__ wbf,
    const float* __restrict__ blv, const float* __restrict__ bmu,
    const int* __restrict__ y, const float* __restrict__ embT,
    float* __restrict__ out, int doEmbed) {
  __shared__ char lds[3 * 16384];                    // 48 KB
  const int tid  = threadIdx.x;
  const int lane = tid & 63;
  const int wid  = tid >> 6;
  const int wm   = wid >> 2;   // 0..1
  const int wn   = wid & 3;    // 0..3
  // XCD-chunked bijective swizzle (nwg=8192 % 8 == 0): each XCD gets a
  // contiguous wg-range; the two col-halves of a row-block share the XCD's L2.
  const unsigned orig = blockIdx.x;
  const unsigned wg   = (orig & 7u) * 1024u + (orig >> 3);
  const int rb = (int)(wg >> 1);
  const int h  = (int)(wg & 1);
  const int gm   = rb << 6;
  const int gcol = h << 7;
  const int lr   = lane & 15;
  const int kg   = lane >> 4;

  // --- staging descriptors (rule 21: linear LDS dest, pre-swizzled source) ---
  // A: 512 chunks; c=tid: row=c>>3 (8 chunks per 128B row), q=c&7, src q^=(row&7)
  const int arow = tid >> 3, aq = tid & 7;
  const unsigned aSrc = (unsigned)(arow << 9) + (unsigned)((aq ^ (arow & 7)) << 2); // fp32 elems
  const unsigned aDst = (unsigned)(tid << 4);
  // B: 512 chunks; c=tid: col=c>>2 (4 chunks per 64B row), q=c&3, src q^=((col>>1)&3)
  const int bcol = tid >> 2, bq = tid & 3;
  const unsigned bSrc = (unsigned)((gcol + bcol) << 9) + (unsigned)((bq ^ ((bcol >> 1) & 3)) << 3); // bf16 elems
  const unsigned bDst = 8192u + (unsigned)(tid << 4);
  const float* xblk = x + ((size_t)gm << 9);

  // --- fragment-read byte offsets within a stage ---
  unsigned offA[2][2], offB[2];
#pragma unroll
  for (int m = 0; m < 2; ++m) {
    int row = (wm << 5) + (m << 4) + lr;
    int sw = row & 7;
    offA[m][0] = (unsigned)(row << 7) + (unsigned)((((kg << 1))     ^ sw) << 4);
    offA[m][1] = (unsigned)(row << 7) + (unsigned)((((kg << 1) + 1) ^ sw) << 4);
  }
#pragma unroll
  for (int nt = 0; nt < 2; ++nt) {
    int col = (wn << 5) + (nt << 4) + lr;
    offB[nt] = 8192u + (unsigned)(col << 6) + (unsigned)((kg ^ ((col >> 1) & 3)) << 4);
  }

  f4v acc[2][2];
#pragma unroll
  for (int m = 0; m < 2; ++m)
#pragma unroll
    for (int nt = 0; nt < 2; ++nt) acc[m][nt] = (f4v)0.f;

#define ISSUE_STAGE(st)                                                            \
  {                                                                                \
    const int ke = (st) << 5;                                                      \
    char* sb = lds + ((st) % 3) * 16384;                                           \
    __builtin_amdgcn_global_load_lds((const gu32_t*)(xblk + aSrc + ke),            \
                                     (lu32_t*)(sb + aDst), 16, 0, 0);              \
    __builtin_amdgcn_global_load_lds((const gu32_t*)(wbf + bSrc + ke),             \
                                     (lu32_t*)(sb + bDst), 16, 0, 0);              \
  }

  // prologue: stages 0,1 in flight; wait stage 0 (2 of 4 ops), sync
  ISSUE_STAGE(0)
  ISSUE_STAGE(1)
  asm volatile("s_waitcnt vmcnt(2)" ::: "memory");
  __builtin_amdgcn_s_barrier();

#pragma unroll
  for (int t = 0; t < 16; ++t) {
    if (t <= 13) ISSUE_STAGE(t + 2)
    const char* stage = lds + (t % 3) * 16384;
    s8v bfr[2];
#pragma unroll
    for (int nt = 0; nt < 2; ++nt)
      bfr[nt] = *(const s8v*)(stage + offB[nt]);
    s8v af[2];
#pragma unroll
    for (int m = 0; m < 2; ++m) {
      float4 a0 = *(const float4*)(stage + offA[m][0]);
      float4 a1 = *(const float4*)(stage + offA[m][1]);
      af[m][0] = f2bf(a0.x); af[m][1] = f2bf(a0.y); af[m][2] = f2bf(a0.z); af[m][3] = f2bf(a0.w);
      af[m][4] = f2bf(a1.x); af[m][5] = f2bf(a1.y); af[m][6] = f2bf(a1.z); af[m][7] = f2bf(a1.w);
    }
#pragma unroll
    for (int m = 0; m < 2; ++m)
#pragma unroll
      for (int nt = 0; nt < 2; ++nt)
        acc[m][nt] = __builtin_amdgcn_mfma_f32_16x16x32_bf16(af[m], bfr[nt], acc[m][nt], 0, 0, 0);
    // retire my LDS reads, then counted vmcnt: t+1 landed, t+2 in flight
    asm volatile("s_waitcnt lgkmcnt(0)" ::: "memory");
    __builtin_amdgcn_sched_barrier(0);
    if (t <= 13)      { asm volatile("s_waitcnt vmcnt(2)" ::: "memory"); }
    else if (t == 14) { asm volatile("s_waitcnt vmcnt(0)" ::: "memory"); }
    if (t <= 14) __builtin_amdgcn_s_barrier();
  }
#undef ISSUE_STAGE

  // epilogue: C/D layout col=lane&15, row=(lane>>4)*4+r (validated r1..r8)
  const int rsub = kg << 2;
#pragma unroll
  for (int nt = 0; nt < 2; ++nt) {
    int col = gcol + (wn << 5) + (nt << 4) + lr;
    float bias = (col < 128) ? blv[col] : bmu[col - 128];
    float* ob = (col < 128) ? (out + col)
                            : (out + ((size_t)NB << 7) + (col - 128));
#pragma unroll
    for (int m = 0; m < 2; ++m) {
      int row0 = gm + (wm << 5) + (m << 4) + rsub;
#pragma unroll
      for (int r = 0; r < 4; ++r)
        ob[(size_t)(row0 + r) << 7] = acc[m][nt][r] + bias;
    }
  }

  // fused embed: h==0 block handles its 64 rows; embT is L2-resident
  if (doEmbed && h == 0) {
    float* out3 = out + ((size_t)NB << 8);
    int r  = tid >> 3;            // 0..63
    int c0 = (tid & 7) << 4;      // 0..112 (floats)
    int row = gm + r;
    int v = y[row];
    const float4* src = (const float4*)(embT + (size_t)v * 128 + c0);
    float4* dst = (float4*)(out3 + ((size_t)row << 7) + c0);
#pragma unroll
    for (int j = 0; j < 4; ++j) dst[j] = src[j];
  }
}

// ---------------- fallbacks (only if ws_size too small) ----------------
__global__ void gemm_naive(const float* __restrict__ x,
                           const float* __restrict__ Wlv, const float* __restrict__ blv,
                           const float* __restrict__ Wmu, const float* __restrict__ bmu,
                           float* __restrict__ out) {
  __shared__ float xr[512];
  int b = blockIdx.x;
  for (int i = threadIdx.x; i < 512; i += 256) xr[i] = x[(size_t)b * 512 + i];
  __syncthreads();
  int c = threadIdx.x;
  const float* w = (c < 128) ? (Wlv + c * 512) : (Wmu + (c - 128) * 512);
  float s = 0.f;
  for (int k = 0; k < 512; ++k) s += xr[k] * w[k];
  s += (c < 128) ? blv[c] : bmu[c - 128];
  float* o = (c < 128) ? (out + (size_t)b * 128 + c)
                       : (out + ((size_t)NB << 7) + (size_t)b * 128 + (c - 128));
  *o = s;
}

__global__ void embed_direct(const int* __restrict__ y, const float* __restrict__ We,
                             const float* __restrict__ be, float* __restrict__ out3) {
  size_t t = (size_t)blockIdx.x * 256 + threadIdx.x;
  int b = (int)(t >> 7), l = (int)(t & 127);
  out3[t] = We[(size_t)l * ED + y[b]] + be[l];
}

extern "C" void kernel_launch(void* const* d_in, const int* in_sizes, int n_in,
                              void* d_out, int out_size, void* d_ws, size_t ws_size,
                              hipStream_t stream) {
  const float* x   = (const float*)d_in[0];
  const int*   y   = (const int*)d_in[1];
  const float* Wlv = (const float*)d_in[2];
  const float* blv = (const float*)d_in[3];
  const float* Wmu = (const float*)d_in[4];
  const float* bmu = (const float*)d_in[5];
  const float* We  = (const float*)d_in[6];
  const float* be  = (const float*)d_in[7];
  float* out  = (float*)d_out;
  float* out3 = out + ((size_t)NB << 8);

  const size_t needW = 256 * 512 * sizeof(unsigned short);          // 256 KB
  const size_t needE = needW + (size_t)ED * 128 * sizeof(float);    // + 5.12 MB
  unsigned short* wbf = (unsigned short*)d_ws;
  float* embT = (float*)((char*)d_ws + needW);

  if (ws_size >= needE) {
    prep_all<<<512 + 313, 256, 0, stream>>>(Wlv, Wmu, wbf, We, be, embT);
    gemm_heads<<<NB / 32, 512, 0, stream>>>(x, wbf, blv, bmu, y, embT, out, 1);
  } else if (ws_size >= needW) {
    prep_all<<<512, 256, 0, stream>>>(Wlv, Wmu, wbf, We, be, (float*)d_ws);
    gemm_heads<<<NB / 32, 512, 0, stream>>>(x, wbf, blv, bmu, y, nullptr, out, 0);
    embed_direct<<<NB * 128 / 256, 256, 0, stream>>>(y, We, be, out3);
  } else {
    gemm_naive<<<NB, 256, 0, stream>>>(x, Wlv, blv, Wmu, bmu, out);
    embed_direct<<<NB * 128 / 256, 256, 0, stream>>>(y, We, be, out3);
  }
}